// Round 18
// baseline (135.622 us; speedup 1.0000x reference)
//
#include <hip/hip_runtime.h>
#include <hip/hip_bf16.h>

#define N_NODES 100000
#define N_EDGES 1200000
#define D_IN 256
#define D_OUT 64
#define N_TILES (N_NODES / 16)                     // 6250 row tiles of 16

#define NG 1280                                    // GEMM blocks = 5/CU x 256
#define FUSED_NB (NG * 2)                          // even: GEMM, odd: edge
#define EDGE4_NB ((N_EDGES / 4 + 255) / 256)       // 1172 (4 edges/thread)

#define FILL_PASSES 2
#define PASS_NODES (N_NODES / FILL_PASSES)         // 50000 (~3MB csr window, L2-resident)
#define FILL_NB ((N_EDGES / 4 + 255) / 256)        // 1172

#define SCAN_BLOCK 1024
#define SCAN_NB ((N_NODES + SCAN_BLOCK - 1) / SCAN_BLOCK) // 98

typedef __bf16 bf16_t;
typedef bf16_t bf16x8 __attribute__((ext_vector_type(8)));
typedef float f32x4 __attribute__((ext_vector_type(4)));

// pack (col, val) into 4B: col<<15 | round(val*32767). val in [0,1).
__device__ __forceinline__ unsigned pack_cv(int col, float val) {
    return ((unsigned)col << 15) | (unsigned)(val * 32767.f + 0.5f);
}

__device__ __forceinline__ bf16x8 cvt8(float4 lo, float4 hi) {
    bf16x8 a;
    a[0] = (bf16_t)lo.x; a[1] = (bf16_t)lo.y;
    a[2] = (bf16_t)lo.z; a[3] = (bf16_t)lo.w;
    a[4] = (bf16_t)hi.x; a[5] = (bf16_t)hi.y;
    a[6] = (bf16_t)hi.z; a[7] = (bf16_t)hi.w;
    return a;
}

// async global->LDS, 16B per lane, dest = wave-uniform base + lane*16
__device__ __forceinline__ void gld_lds16(const void* g, void* l) {
    __builtin_amdgcn_global_load_lds(
        (const __attribute__((address_space(1))) void*)g,
        (__attribute__((address_space(3))) void*)l, 16, 0, 0);
}

// ---------------------------------------------------------------------------
// Kernel 1: pack W[256][64] (fp32) into MFMA B-fragment order, bf16.
// ---------------------------------------------------------------------------
__global__ __launch_bounds__(256) void pack_w(const float* __restrict__ W,
                                              bf16_t* __restrict__ Wpack) {
    int id = blockIdx.x * 256 + threadIdx.x;
    if (id < D_IN * D_OUT) {
        int i  = id & 7;
        int l  = (id >> 3) & 63;
        int n  = (id >> 9) & 3;
        int kk = id >> 11;
        int k = kk * 32 + (l >> 4) * 8 + i;
        int c = n * 16 + (l & 15);
        Wpack[id] = (bf16_t)W[k * D_OUT + c];
    }
}

// Stage one x tile (16 rows x 256 f32 = 16KB) into LDS, [kk][half][lane]x16B
// layout; per-lane-permuted global src, linear LDS dest (wave base + lane*16).
__device__ __forceinline__ void stage_tile(const char* __restrict__ xtile,
                                           char* ldsbuf, int wave, int lane) {
#pragma unroll
    for (int i = 0; i < 4; ++i) {
        int kk = i * 2 + (wave >> 1);
        const char* src = xtile + (lane & 15) * 1024 + (lane >> 4) * 32
                        + kk * 128 + (wave & 1) * 16;
        gld_lds16(src, ldsbuf + i * 4096 + wave * 1024);
    }
}

// Compute one tile from LDS, store its 16x16 output sub-tile (cols wave*16..).
__device__ __forceinline__ void compute_store(const char* buf,
                                              const bf16x8* wf,
                                              int lane, int lrow, int g, int wave,
                                              bf16_t* __restrict__ support,
                                              int tile) {
    f32x4 acc = {0.f, 0.f, 0.f, 0.f};
#pragma unroll
    for (int kk = 0; kk < 8; ++kk) {
        float4 lo = *(const float4*)(buf + kk * 2048 + lane * 16);
        float4 hi = *(const float4*)(buf + kk * 2048 + 1024 + lane * 16);
        acc = __builtin_amdgcn_mfma_f32_16x16x32_bf16(cvt8(lo, hi), wf[kk],
                                                      acc, 0, 0, 0);
    }
    bf16_t* __restrict__ sp = support + (size_t)tile * 16 * D_OUT
                            + wave * 16 + lrow;
#pragma unroll
    for (int q = 0; q < 4; ++q)
        sp[(g * 4 + q) * D_OUT] = (bf16_t)acc[q];
}

// ---------------------------------------------------------------------------
// Kernel 2 (fused, role-split — R13/R14 proven structure): even blocks =
// GEMM (double-buffered global_load_lds pipeline, counted vmcnt); odd =
// edge chunk (hist atomics capturing pos, rcv pack).
// vmcnt FIFO accounting: first iter [8 wf][4 stage0][4 stage1] -> vmcnt(4);
// steady [4L t][4S t-1][4L t+1] -> vmcnt(8); last [4L t][4S] -> vmcnt(4).
// ---------------------------------------------------------------------------
__global__ __launch_bounds__(256, 5) void gemm_hist_cv(
        const float* __restrict__ x, const bf16x8* __restrict__ Wpack,
        bf16_t* __restrict__ support,
        const int* __restrict__ erow, const int* __restrict__ ecol,
        const float* __restrict__ eval,
        int* __restrict__ counts, unsigned* __restrict__ rcv) {
    __shared__ char xlds[2][16384];                // 32 KB double buffer
    int bid  = blockIdx.x;
    int role = bid & 1;
    int idx  = bid >> 1;
    if (role == 0) {
        // ---------------- GEMM role ----------------
        int lane = threadIdx.x & 63;
        int wave = threadIdx.x >> 6;
        int lrow = lane & 15;
        int g    = lane >> 4;

        // W fragments FIRST (oldest in VMEM FIFO; retired by first vmcnt(4))
        bf16x8 wf[8];
#pragma unroll
        for (int kk = 0; kk < 8; ++kk)
            wf[kk] = Wpack[(kk * 4 + wave) * 64 + lane];

        const char* xc = (const char*)x;
        int t = idx;                               // idx in [0, NG)
        stage_tile(xc + (size_t)t * 16384, xlds[0], wave, lane);

        int cur = 0;
#pragma unroll 1
        for (; t < N_TILES; t += NG) {
            int nxt = t + NG;
            if (nxt < N_TILES) {
                stage_tile(xc + (size_t)nxt * 16384, xlds[cur ^ 1], wave, lane);
                if (t == idx) {
                    asm volatile("s_waitcnt vmcnt(4)" ::: "memory");
                } else {
                    asm volatile("s_waitcnt vmcnt(8)" ::: "memory");
                }
            } else {
                asm volatile("s_waitcnt vmcnt(4)" ::: "memory");
            }
            __builtin_amdgcn_s_barrier();          // staged data visible
            __builtin_amdgcn_sched_barrier(0);     // pin ds_reads below
            compute_store(xlds[cur], wf, lane, lrow, g, wave, support, t);
            __builtin_amdgcn_s_barrier();          // all waves done reading
            __builtin_amdgcn_sched_barrier(0);     // pin next stage below
            cur ^= 1;
        }
    } else {
        // ---- edge role: histogram + pos capture + rcv pack ----
        if (idx >= EDGE4_NB) return;
        int e = (idx * 256 + threadIdx.x) * 4;
        if (e + 3 < N_EDGES) {
            int4   r4 = *(const int4*)(erow + e);
            int4   c4 = *(const int4*)(ecol + e);
            float4 v4 = *(const float4*)(eval + e);
            unsigned p0 = (unsigned)atomicAdd(&counts[r4.x], 1);
            unsigned p1 = (unsigned)atomicAdd(&counts[r4.y], 1);
            unsigned p2 = (unsigned)atomicAdd(&counts[r4.z], 1);
            unsigned p3 = (unsigned)atomicAdd(&counts[r4.w], 1);
            uint4 o1, o2;
            o1.x = pack_cv(c4.x, v4.x); o1.y = (unsigned)r4.x | (p0 << 17);
            o1.z = pack_cv(c4.y, v4.y); o1.w = (unsigned)r4.y | (p1 << 17);
            o2.x = pack_cv(c4.z, v4.z); o2.y = (unsigned)r4.z | (p2 << 17);
            o2.z = pack_cv(c4.w, v4.w); o2.w = (unsigned)r4.w | (p3 << 17);
            *(uint4*)(rcv + 2 * e)     = o1;
            *(uint4*)(rcv + 2 * e + 4) = o2;
        } else {
            for (int i = 0; i < 4; ++i) {
                if (e + i < N_EDGES) {
                    int rr = erow[e + i];
                    unsigned pp = (unsigned)atomicAdd(&counts[rr], 1);
                    rcv[2 * (e + i)]     = pack_cv(ecol[e + i], eval[e + i]);
                    rcv[2 * (e + i) + 1] = (unsigned)rr | (pp << 17);
                }
            }
        }
    }
}

// ---------------------------------------------------------------------------
// Kernel 3 (merged scan): each block redundantly computes the global
// prefix of ceil4(counts) before its chunk (L2-resident reads), then
// scans its own 1024-count chunk -> offsets. Single launch.
// ---------------------------------------------------------------------------
__global__ __launch_bounds__(256) void scan_emit_k(const int* __restrict__ counts,
                                                   int* __restrict__ offsets) {
    __shared__ int sh[256];
    __shared__ int sw[4];
    int b = blockIdx.x, t = threadIdx.x;

    // phase 1: pre = sum of ceil4(counts[0 .. b*1024))
    int limit = b * SCAN_BLOCK;
    int pre = 0;
    for (int base = t * 4; base + 3 < limit; base += 1024) {
        int4 v = *(const int4*)(counts + base);
        pre += ((v.x + 3) & ~3) + ((v.y + 3) & ~3)
             + ((v.z + 3) & ~3) + ((v.w + 3) & ~3);
    }
#pragma unroll
    for (int off = 32; off > 0; off >>= 1) pre += __shfl_down(pre, off);
    if ((t & 63) == 0) sw[t >> 6] = pre;
    __syncthreads();
    int bpre = sw[0] + sw[1] + sw[2] + sw[3];

    // phase 2: block-local scan of this chunk
    int base = b * SCAN_BLOCK + t * 4;
    int c0 = 0, c1 = 0, c2 = 0, c3 = 0;
    if (base + 3 < N_NODES) {
        int4 v = *(const int4*)(counts + base);
        c0 = (v.x + 3) & ~3; c1 = (v.y + 3) & ~3;
        c2 = (v.z + 3) & ~3; c3 = (v.w + 3) & ~3;
    } else {
        if (base + 0 < N_NODES) c0 = (counts[base + 0] + 3) & ~3;
        if (base + 1 < N_NODES) c1 = (counts[base + 1] + 3) & ~3;
        if (base + 2 < N_NODES) c2 = (counts[base + 2] + 3) & ~3;
        if (base + 3 < N_NODES) c3 = (counts[base + 3] + 3) & ~3;
    }
    int sum4 = c0 + c1 + c2 + c3;
    sh[t] = sum4;
    __syncthreads();
    for (int off = 1; off < 256; off <<= 1) {
        int add = (t >= off) ? sh[t - off] : 0;
        __syncthreads();
        sh[t] += add;
        __syncthreads();
    }
    int run = bpre + sh[t] - sum4;
    if (base + 0 < N_NODES) { offsets[base + 0] = run; run += c0; }
    if (base + 1 < N_NODES) { offsets[base + 1] = run; run += c1; }
    if (base + 2 < N_NODES) { offsets[base + 2] = run; run += c2; }
    if (base + 3 < N_NODES) { offsets[base + 3] = run; run += c3; }
}

// ---------------------------------------------------------------------------
// Kernel 4: atomic-free predicated CSR fill: dst = offsets[row] + pos.
// 2 passes, each confined to a ~3MB (L2-resident) csr window [lo, hi).
// ---------------------------------------------------------------------------
__global__ __launch_bounds__(256) void fill_k(const unsigned* __restrict__ rcv,
                                              const int* __restrict__ offsets,
                                              unsigned* __restrict__ csr,
                                              int lo, int hi) {
    int t = blockIdx.x * 256 + threadIdx.x;
    int e = t * 4;
    if (e + 3 < N_EDGES) {
        uint4 A = *(const uint4*)(rcv + 2 * e);
        uint4 B = *(const uint4*)(rcv + 2 * e + 4);
        int r0 = (int)(A.y & 0x1ffffu), p0 = (int)(A.y >> 17);
        int r1 = (int)(A.w & 0x1ffffu), p1 = (int)(A.w >> 17);
        int r2 = (int)(B.y & 0x1ffffu), p2 = (int)(B.y >> 17);
        int r3 = (int)(B.w & 0x1ffffu), p3 = (int)(B.w >> 17);
        int o0 = offsets[r0];
        int o1 = offsets[r1];
        int o2 = offsets[r2];
        int o3 = offsets[r3];
        if (r0 >= lo && r0 < hi) csr[o0 + p0] = A.x;
        if (r1 >= lo && r1 < hi) csr[o1 + p1] = A.z;
        if (r2 >= lo && r2 < hi) csr[o2 + p2] = B.x;
        if (r3 >= lo && r3 < hi) csr[o3 + p3] = B.z;
    } else {
        for (int i = 0; i < 4; ++i) {
            if (e + i < N_EDGES) {
                unsigned cw = rcv[2 * (e + i)];
                unsigned rw = rcv[2 * (e + i) + 1];
                int rr = (int)(rw & 0x1ffffu);
                int pp = (int)(rw >> 17);
                if (rr >= lo && rr < hi) csr[offsets[rr] + pp] = cw;
            }
        }
    }
}

// ---------------------------------------------------------------------------
// Kernel 5: aggregate + ReLU. 4 nodes/wave (16 lanes x uint2 per node);
// nontemporal f32x4 output stores (streaming write, don't evict
// L2-resident support lines that the gathers re-use).
// ---------------------------------------------------------------------------
__global__ __launch_bounds__(256) void agg_k(const int* __restrict__ offsets,
                                             const int* __restrict__ counts,
                                             const unsigned* __restrict__ csr,
                                             const uint2* __restrict__ supq,
                                             float* __restrict__ out) {
    int wave = threadIdx.x >> 6;
    int lane = threadIdx.x & 63;
    int q4   = lane >> 4;
    int fl   = lane & 15;
    int node = blockIdx.x * 16 + wave * 4 + q4;
    if (node >= N_NODES) return;
    int s = offsets[node];
    int e = s + counts[node];
    const float inv = 1.f / 32767.f;
    float a0 = 0.f, a1 = 0.f, a2 = 0.f, a3 = 0.f;
    int p = s;
#define ACC(w, qq) { float v = (float)((w) & 0x7fffu) * inv;                    \
        a0 = fmaf(v, __uint_as_float((qq).x << 16), a0);                        \
        a1 = fmaf(v, __uint_as_float((qq).x & 0xffff0000u), a1);                \
        a2 = fmaf(v, __uint_as_float((qq).y << 16), a2);                        \
        a3 = fmaf(v, __uint_as_float((qq).y & 0xffff0000u), a3); }
    for (; p + 8 <= e; p += 8) {
        uint4 A = *(const uint4*)(csr + p);
        uint4 B = *(const uint4*)(csr + p + 4);
        uint2 q0 = supq[(size_t)(A.x >> 15) * 16 + fl];
        uint2 q1 = supq[(size_t)(A.y >> 15) * 16 + fl];
        uint2 q2 = supq[(size_t)(A.z >> 15) * 16 + fl];
        uint2 q3 = supq[(size_t)(A.w >> 15) * 16 + fl];
        uint2 q4v = supq[(size_t)(B.x >> 15) * 16 + fl];
        uint2 q5 = supq[(size_t)(B.y >> 15) * 16 + fl];
        uint2 q6 = supq[(size_t)(B.z >> 15) * 16 + fl];
        uint2 q7 = supq[(size_t)(B.w >> 15) * 16 + fl];
        ACC(A.x, q0) ACC(A.y, q1) ACC(A.z, q2) ACC(A.w, q3)
        ACC(B.x, q4v) ACC(B.y, q5) ACC(B.z, q6) ACC(B.w, q7)
    }
    if (p + 4 <= e) {
        uint4 A = *(const uint4*)(csr + p);
        uint2 q0 = supq[(size_t)(A.x >> 15) * 16 + fl];
        uint2 q1 = supq[(size_t)(A.y >> 15) * 16 + fl];
        uint2 q2 = supq[(size_t)(A.z >> 15) * 16 + fl];
        uint2 q3 = supq[(size_t)(A.w >> 15) * 16 + fl];
        ACC(A.x, q0) ACC(A.y, q1) ACC(A.z, q2) ACC(A.w, q3)
        p += 4;
    }
    for (; p < e; ++p) {
        unsigned w = csr[p];
        uint2 q = supq[(size_t)(w >> 15) * 16 + fl];
        ACC(w, q)
    }
#undef ACC
    f32x4 r;
    r[0] = fmaxf(a0, 0.f);
    r[1] = fmaxf(a1, 0.f);
    r[2] = fmaxf(a2, 0.f);
    r[3] = fmaxf(a3, 0.f);
    __builtin_nontemporal_store(r, (f32x4*)(out + (size_t)node * D_OUT + fl * 4));
}

extern "C" void kernel_launch(void* const* d_in, const int* in_sizes, int n_in,
                              void* d_out, int out_size, void* d_ws, size_t ws_size,
                              hipStream_t stream) {
    const float* x    = (const float*)d_in[0];
    const int*   erow = (const int*)d_in[1];
    const int*   ecol = (const int*)d_in[2];
    const float* eval = (const float*)d_in[3];
    const float* W    = (const float*)d_in[4];
    float* out = (float*)d_out;

    // ---- workspace layout (16B-aligned segments, ~29.3 MB) ----
    char* ws = (char*)d_ws;
    bf16_t*   support = (bf16_t*)ws;                         // 12,800,000
    bf16_t*   WpackS  = (bf16_t*)(ws + 12800000);            //     32,768
    int*      counts  = (int*)(ws + 12832768);               //    400,000
    int*      offsets = (int*)(ws + 13232768);               //    400,016
    unsigned* rcv     = (unsigned*)(ws + 13632784);          //  9,600,000
    unsigned* csr     = (unsigned*)(ws + 23232784);          //  6,000,000 (padded)

    // 1) pack W into bf16 MFMA B-fragments
    pack_w<<<(D_IN * D_OUT + 255) / 256, 256, 0, stream>>>(W, WpackS);

    // 2) zero counts, then fused role-split GEMM + edge (hist + pos + rcv)
    (void)hipMemsetAsync(counts, 0, (size_t)N_NODES * sizeof(int), stream);
    gemm_hist_cv<<<FUSED_NB, 256, 0, stream>>>(
        x, (const bf16x8*)WpackS, support, erow, ecol, eval, counts, rcv);

    // 3) merged scan (single launch) -> quad-aligned offsets
    scan_emit_k<<<SCAN_NB, 256, 0, stream>>>(counts, offsets);

    // 4) atomic-free predicated CSR fill, 2 L2-localized passes
    for (int p = 0; p < FILL_PASSES; ++p) {
        fill_k<<<FILL_NB, 256, 0, stream>>>(rcv, offsets, csr,
                                            p * PASS_NODES, (p + 1) * PASS_NODES);
    }

    // 5) aggregate + ReLU (no atomics, writes every output element)
    agg_k<<<(N_NODES + 15) / 16, 256, 0, stream>>>(offsets, counts, csr,
                                                   (const uint2*)support, out);
}

// Round 19
// 119.375 us; speedup vs baseline: 1.1361x; 1.1361x over previous
//
#include <hip/hip_runtime.h>
#include <hip/hip_bf16.h>

#define N_NODES 100000
#define N_EDGES 1200000
#define D_IN 256
#define D_OUT 64
#define N_TILES (N_NODES / 16)                     // 6250 row tiles of 16

#define NG 1280                                    // GEMM blocks = 5/CU x 256
#define FUSED_NB (NG * 2)                          // even: GEMM, odd: edge
#define EDGE4_NB ((N_EDGES / 4 + 255) / 256)       // 1172 (4 edges/thread)

#define FILL_PASSES 2
#define PASS_NODES (N_NODES / FILL_PASSES)         // 50000 (~3MB csr window, L2-resident)
#define FILL_NB ((N_EDGES / 4 + 255) / 256)        // 1172

#define SCAN_BLOCK 1024
#define SCAN_NB ((N_NODES + SCAN_BLOCK - 1) / SCAN_BLOCK) // 98

typedef __bf16 bf16_t;
typedef bf16_t bf16x8 __attribute__((ext_vector_type(8)));
typedef float f32x4 __attribute__((ext_vector_type(4)));

// pack (col, val) into 4B: col<<15 | round(val*32767). val in [0,1).
__device__ __forceinline__ unsigned pack_cv(int col, float val) {
    return ((unsigned)col << 15) | (unsigned)(val * 32767.f + 0.5f);
}

__device__ __forceinline__ bf16x8 cvt8(float4 lo, float4 hi) {
    bf16x8 a;
    a[0] = (bf16_t)lo.x; a[1] = (bf16_t)lo.y;
    a[2] = (bf16_t)lo.z; a[3] = (bf16_t)lo.w;
    a[4] = (bf16_t)hi.x; a[5] = (bf16_t)hi.y;
    a[6] = (bf16_t)hi.z; a[7] = (bf16_t)hi.w;
    return a;
}

// async global->LDS, 16B per lane, dest = wave-uniform base + lane*16
__device__ __forceinline__ void gld_lds16(const void* g, void* l) {
    __builtin_amdgcn_global_load_lds(
        (const __attribute__((address_space(1))) void*)g,
        (__attribute__((address_space(3))) void*)l, 16, 0, 0);
}

// ---------------------------------------------------------------------------
// Kernel 1: pack W[256][64] (fp32) into MFMA B-fragment order, bf16.
// Also zeros counts[] (grid-stride int4) -> drops the memset launch.
// ---------------------------------------------------------------------------
__global__ __launch_bounds__(256) void pack_w(const float* __restrict__ W,
                                              bf16_t* __restrict__ Wpack,
                                              int* __restrict__ counts) {
    int id = blockIdx.x * 256 + threadIdx.x;
    if (id < D_IN * D_OUT) {
        int i  = id & 7;
        int l  = (id >> 3) & 63;
        int n  = (id >> 9) & 3;
        int kk = id >> 11;
        int k = kk * 32 + (l >> 4) * 8 + i;
        int c = n * 16 + (l & 15);
        Wpack[id] = (bf16_t)W[k * D_OUT + c];
    }
    for (int i = id; i < N_NODES / 4; i += (D_IN * D_OUT / 256) * 256)
        ((int4*)counts)[i] = make_int4(0, 0, 0, 0);
}

// ---------------------------------------------------------------------------
// Stage one x tile (16 rows x 1KB) into LDS, ONE FULL ROW PER INSTRUCTION:
// 64 lanes x 16B = 1KB contiguous global read (2 merged runs after the
// rotation) -> ~2 TA requests per instruction instead of ~64 scattered 16B.
// Rotation swizzle: slot s of row r holds chunk (s + r) & 63 (source is
// per-lane, LDS dest stays linear base + lane*16 as HW requires).
// Wave w stages rows {w, w+4, w+8, w+12} -> 4 issues/thread (vmcnt math
// unchanged).
// ---------------------------------------------------------------------------
__device__ __forceinline__ void stage_tile(const char* __restrict__ xtile,
                                           char* ldsbuf, int wave, int lane) {
#pragma unroll
    for (int i = 0; i < 4; ++i) {
        int r = wave + i * 4;
        const char* src = xtile + r * 1024 + (((lane + r) & 63) << 4);
        gld_lds16(src, ldsbuf + r * 1024);
    }
}

// Compute one tile from LDS (rotation-inverted reads), store its 16x16
// output sub-tile (cols wave*16..). Chunk c of row lrow lives at LDS slot
// (c - lrow) & 63. Bank profile: 8 accesses/bank = b128 minimum.
__device__ __forceinline__ void compute_store(const char* buf,
                                              const bf16x8* wf,
                                              int lane, int lrow, int g, int wave,
                                              bf16_t* __restrict__ support,
                                              int tile) {
    f32x4 acc = {0.f, 0.f, 0.f, 0.f};
    const char* rowp = buf + lrow * 1024;
#pragma unroll
    for (int kk = 0; kk < 8; ++kk) {
        int c = kk * 8 + g * 2;
        float4 lo = *(const float4*)(rowp + (((c     - lrow) & 63) << 4));
        float4 hi = *(const float4*)(rowp + (((c + 1 - lrow) & 63) << 4));
        acc = __builtin_amdgcn_mfma_f32_16x16x32_bf16(cvt8(lo, hi), wf[kk],
                                                      acc, 0, 0, 0);
    }
    bf16_t* __restrict__ sp = support + (size_t)tile * 16 * D_OUT
                            + wave * 16 + lrow;
#pragma unroll
    for (int q = 0; q < 4; ++q)
        sp[(g * 4 + q) * D_OUT] = (bf16_t)acc[q];
}

// ---------------------------------------------------------------------------
// Kernel 2 (fused, role-split — R13/R14 proven structure): even blocks =
// GEMM (double-buffered global_load_lds pipeline, counted vmcnt); odd =
// edge chunk (hist atomics capturing pos, rcv pack).
// vmcnt FIFO: first iter [8 wf][4 stage0][4 stage1] -> vmcnt(4);
// steady [4L t][4S t-1][4L t+1] -> vmcnt(8); last [4L t][4S] -> vmcnt(4).
// ---------------------------------------------------------------------------
__global__ __launch_bounds__(256, 5) void gemm_hist_cv(
        const float* __restrict__ x, const bf16x8* __restrict__ Wpack,
        bf16_t* __restrict__ support,
        const int* __restrict__ erow, const int* __restrict__ ecol,
        const float* __restrict__ eval,
        int* __restrict__ counts, unsigned* __restrict__ rcv) {
    __shared__ char xlds[2][16384];                // 32 KB double buffer
    int bid  = blockIdx.x;
    int role = bid & 1;
    int idx  = bid >> 1;
    if (role == 0) {
        // ---------------- GEMM role ----------------
        int lane = threadIdx.x & 63;
        int wave = threadIdx.x >> 6;
        int lrow = lane & 15;
        int g    = lane >> 4;

        // W fragments FIRST (oldest in VMEM FIFO; retired by first vmcnt(4))
        bf16x8 wf[8];
#pragma unroll
        for (int kk = 0; kk < 8; ++kk)
            wf[kk] = Wpack[(kk * 4 + wave) * 64 + lane];

        const char* xc = (const char*)x;
        int t = idx;                               // idx in [0, NG)
        stage_tile(xc + (size_t)t * 16384, xlds[0], wave, lane);

        int cur = 0;
#pragma unroll 1
        for (; t < N_TILES; t += NG) {
            int nxt = t + NG;
            if (nxt < N_TILES) {
                stage_tile(xc + (size_t)nxt * 16384, xlds[cur ^ 1], wave, lane);
                if (t == idx) {
                    asm volatile("s_waitcnt vmcnt(4)" ::: "memory");
                } else {
                    asm volatile("s_waitcnt vmcnt(8)" ::: "memory");
                }
            } else {
                asm volatile("s_waitcnt vmcnt(4)" ::: "memory");
            }
            __builtin_amdgcn_s_barrier();          // staged data visible
            __builtin_amdgcn_sched_barrier(0);     // pin ds_reads below
            compute_store(xlds[cur], wf, lane, lrow, g, wave, support, t);
            __builtin_amdgcn_s_barrier();          // all waves done reading
            __builtin_amdgcn_sched_barrier(0);     // pin next stage below
            cur ^= 1;
        }
    } else {
        // ---- edge role: histogram + pos capture + rcv pack ----
        if (idx >= EDGE4_NB) return;
        int e = (idx * 256 + threadIdx.x) * 4;
        if (e + 3 < N_EDGES) {
            int4   r4 = *(const int4*)(erow + e);
            int4   c4 = *(const int4*)(ecol + e);
            float4 v4 = *(const float4*)(eval + e);
            unsigned p0 = (unsigned)atomicAdd(&counts[r4.x], 1);
            unsigned p1 = (unsigned)atomicAdd(&counts[r4.y], 1);
            unsigned p2 = (unsigned)atomicAdd(&counts[r4.z], 1);
            unsigned p3 = (unsigned)atomicAdd(&counts[r4.w], 1);
            uint4 o1, o2;
            o1.x = pack_cv(c4.x, v4.x); o1.y = (unsigned)r4.x | (p0 << 17);
            o1.z = pack_cv(c4.y, v4.y); o1.w = (unsigned)r4.y | (p1 << 17);
            o2.x = pack_cv(c4.z, v4.z); o2.y = (unsigned)r4.z | (p2 << 17);
            o2.z = pack_cv(c4.w, v4.w); o2.w = (unsigned)r4.w | (p3 << 17);
            *(uint4*)(rcv + 2 * e)     = o1;
            *(uint4*)(rcv + 2 * e + 4) = o2;
        } else {
            for (int i = 0; i < 4; ++i) {
                if (e + i < N_EDGES) {
                    int rr = erow[e + i];
                    unsigned pp = (unsigned)atomicAdd(&counts[rr], 1);
                    rcv[2 * (e + i)]     = pack_cv(ecol[e + i], eval[e + i]);
                    rcv[2 * (e + i) + 1] = (unsigned)rr | (pp << 17);
                }
            }
        }
    }
}

// ---------------------------------------------------------------------------
// Kernel 3a: per-block partial sums of ceil4(counts) (quad-aligned segments).
// ---------------------------------------------------------------------------
__global__ __launch_bounds__(256) void partial_k(const int* __restrict__ counts,
                                                 int* __restrict__ bsum) {
    int b = blockIdx.x, t = threadIdx.x;
    int base = b * SCAN_BLOCK + t * 4;
    int s = 0;
    if (base + 3 < N_NODES) {
        int4 v = *(const int4*)(counts + base);
        s = ((v.x + 3) & ~3) + ((v.y + 3) & ~3) + ((v.z + 3) & ~3) + ((v.w + 3) & ~3);
    } else {
#pragma unroll
        for (int i = 0; i < 4; ++i)
            if (base + i < N_NODES) s += (counts[base + i] + 3) & ~3;
    }
#pragma unroll
    for (int off = 32; off > 0; off >>= 1) s += __shfl_down(s, off);
    __shared__ int sh[4];
    if ((t & 63) == 0) sh[t >> 6] = s;
    __syncthreads();
    if (t == 0) bsum[b] = sh[0] + sh[1] + sh[2] + sh[3];
}

// ---------------------------------------------------------------------------
// Kernel 3b: emit (merged with bsum scan): each block locally scans the 98
// block sums in LDS, then block-local scan of ceil4 degrees -> offsets.
// ---------------------------------------------------------------------------
__global__ __launch_bounds__(256) void emit_k(const int* __restrict__ counts,
                                              const int* __restrict__ bsum,
                                              int* __restrict__ offsets) {
    __shared__ int sb[128];
    __shared__ int sh[256];
    int b = blockIdx.x, t = threadIdx.x;
    if (t < 128) sb[t] = (t < SCAN_NB) ? bsum[t] : 0;
    __syncthreads();
    for (int off = 1; off < 128; off <<= 1) {
        int add = (t < 128 && t >= off) ? sb[t - off] : 0;
        __syncthreads();
        if (t < 128) sb[t] += add;
        __syncthreads();
    }
    int bpre = (b == 0) ? 0 : sb[b - 1];

    int base = b * SCAN_BLOCK + t * 4;
    int c0 = 0, c1 = 0, c2 = 0, c3 = 0;
    if (base + 3 < N_NODES) {
        int4 v = *(const int4*)(counts + base);
        c0 = (v.x + 3) & ~3; c1 = (v.y + 3) & ~3;
        c2 = (v.z + 3) & ~3; c3 = (v.w + 3) & ~3;
    } else {
        if (base + 0 < N_NODES) c0 = (counts[base + 0] + 3) & ~3;
        if (base + 1 < N_NODES) c1 = (counts[base + 1] + 3) & ~3;
        if (base + 2 < N_NODES) c2 = (counts[base + 2] + 3) & ~3;
        if (base + 3 < N_NODES) c3 = (counts[base + 3] + 3) & ~3;
    }
    int sum4 = c0 + c1 + c2 + c3;
    sh[t] = sum4;
    __syncthreads();
    for (int off = 1; off < 256; off <<= 1) {
        int add = (t >= off) ? sh[t - off] : 0;
        __syncthreads();
        sh[t] += add;
        __syncthreads();
    }
    int run = bpre + sh[t] - sum4;
    if (base + 0 < N_NODES) { offsets[base + 0] = run; run += c0; }
    if (base + 1 < N_NODES) { offsets[base + 1] = run; run += c1; }
    if (base + 2 < N_NODES) { offsets[base + 2] = run; run += c2; }
    if (base + 3 < N_NODES) { offsets[base + 3] = run; run += c3; }
}

// ---------------------------------------------------------------------------
// Kernel 4: atomic-free predicated CSR fill: dst = offsets[row] + pos.
// 2 passes, each confined to a ~3MB (L2-resident) csr window [lo, hi).
// ---------------------------------------------------------------------------
__global__ __launch_bounds__(256) void fill_k(const unsigned* __restrict__ rcv,
                                              const int* __restrict__ offsets,
                                              unsigned* __restrict__ csr,
                                              int lo, int hi) {
    int t = blockIdx.x * 256 + threadIdx.x;
    int e = t * 4;
    if (e + 3 < N_EDGES) {
        uint4 A = *(const uint4*)(rcv + 2 * e);
        uint4 B = *(const uint4*)(rcv + 2 * e + 4);
        int r0 = (int)(A.y & 0x1ffffu), p0 = (int)(A.y >> 17);
        int r1 = (int)(A.w & 0x1ffffu), p1 = (int)(A.w >> 17);
        int r2 = (int)(B.y & 0x1ffffu), p2 = (int)(B.y >> 17);
        int r3 = (int)(B.w & 0x1ffffu), p3 = (int)(B.w >> 17);
        int o0 = offsets[r0];
        int o1 = offsets[r1];
        int o2 = offsets[r2];
        int o3 = offsets[r3];
        if (r0 >= lo && r0 < hi) csr[o0 + p0] = A.x;
        if (r1 >= lo && r1 < hi) csr[o1 + p1] = A.z;
        if (r2 >= lo && r2 < hi) csr[o2 + p2] = B.x;
        if (r3 >= lo && r3 < hi) csr[o3 + p3] = B.z;
    } else {
        for (int i = 0; i < 4; ++i) {
            if (e + i < N_EDGES) {
                unsigned cw = rcv[2 * (e + i)];
                unsigned rw = rcv[2 * (e + i) + 1];
                int rr = (int)(rw & 0x1ffffu);
                int pp = (int)(rw >> 17);
                if (rr >= lo && rr < hi) csr[offsets[rr] + pp] = cw;
            }
        }
    }
}

// ---------------------------------------------------------------------------
// Kernel 5: aggregate + ReLU. 4 nodes/wave (16 lanes x uint2 per node);
// 32 outstanding gathers/wave; regular float4 output stores (R14-proven).
// ---------------------------------------------------------------------------
__global__ __launch_bounds__(256) void agg_k(const int* __restrict__ offsets,
                                             const int* __restrict__ counts,
                                             const unsigned* __restrict__ csr,
                                             const uint2* __restrict__ supq,
                                             float* __restrict__ out) {
    int wave = threadIdx.x >> 6;
    int lane = threadIdx.x & 63;
    int q4   = lane >> 4;
    int fl   = lane & 15;
    int node = blockIdx.x * 16 + wave * 4 + q4;
    if (node >= N_NODES) return;
    int s = offsets[node];
    int e = s + counts[node];
    const float inv = 1.f / 32767.f;
    float a0 = 0.f, a1 = 0.f, a2 = 0.f, a3 = 0.f;
    int p = s;
#define ACC(w, qq) { float v = (float)((w) & 0x7fffu) * inv;                    \
        a0 = fmaf(v, __uint_as_float((qq).x << 16), a0);                        \
        a1 = fmaf(v, __uint_as_float((qq).x & 0xffff0000u), a1);                \
        a2 = fmaf(v, __uint_as_float((qq).y << 16), a2);                        \
        a3 = fmaf(v, __uint_as_float((qq).y & 0xffff0000u), a3); }
    for (; p + 8 <= e; p += 8) {
        uint4 A = *(const uint4*)(csr + p);
        uint4 B = *(const uint4*)(csr + p + 4);
        uint2 q0 = supq[(size_t)(A.x >> 15) * 16 + fl];
        uint2 q1 = supq[(size_t)(A.y >> 15) * 16 + fl];
        uint2 q2 = supq[(size_t)(A.z >> 15) * 16 + fl];
        uint2 q3 = supq[(size_t)(A.w >> 15) * 16 + fl];
        uint2 q4v = supq[(size_t)(B.x >> 15) * 16 + fl];
        uint2 q5 = supq[(size_t)(B.y >> 15) * 16 + fl];
        uint2 q6 = supq[(size_t)(B.z >> 15) * 16 + fl];
        uint2 q7 = supq[(size_t)(B.w >> 15) * 16 + fl];
        ACC(A.x, q0) ACC(A.y, q1) ACC(A.z, q2) ACC(A.w, q3)
        ACC(B.x, q4v) ACC(B.y, q5) ACC(B.z, q6) ACC(B.w, q7)
    }
    if (p + 4 <= e) {
        uint4 A = *(const uint4*)(csr + p);
        uint2 q0 = supq[(size_t)(A.x >> 15) * 16 + fl];
        uint2 q1 = supq[(size_t)(A.y >> 15) * 16 + fl];
        uint2 q2 = supq[(size_t)(A.z >> 15) * 16 + fl];
        uint2 q3 = supq[(size_t)(A.w >> 15) * 16 + fl];
        ACC(A.x, q0) ACC(A.y, q1) ACC(A.z, q2) ACC(A.w, q3)
        p += 4;
    }
    for (; p < e; ++p) {
        unsigned w = csr[p];
        uint2 q = supq[(size_t)(w >> 15) * 16 + fl];
        ACC(w, q)
    }
#undef ACC
    float4 r;
    r.x = fmaxf(a0, 0.f);
    r.y = fmaxf(a1, 0.f);
    r.z = fmaxf(a2, 0.f);
    r.w = fmaxf(a3, 0.f);
    *(float4*)(out + (size_t)node * D_OUT + fl * 4) = r;
}

extern "C" void kernel_launch(void* const* d_in, const int* in_sizes, int n_in,
                              void* d_out, int out_size, void* d_ws, size_t ws_size,
                              hipStream_t stream) {
    const float* x    = (const float*)d_in[0];
    const int*   erow = (const int*)d_in[1];
    const int*   ecol = (const int*)d_in[2];
    const float* eval = (const float*)d_in[3];
    const float* W    = (const float*)d_in[4];
    float* out = (float*)d_out;

    // ---- workspace layout (16B-aligned segments, ~29.3 MB) ----
    char* ws = (char*)d_ws;
    bf16_t*   support = (bf16_t*)ws;                         // 12,800,000
    bf16_t*   WpackS  = (bf16_t*)(ws + 12800000);            //     32,768
    int*      counts  = (int*)(ws + 12832768);               //    400,000
    int*      offsets = (int*)(ws + 13232768);               //    400,016
    unsigned* rcv     = (unsigned*)(ws + 13632784);          //  9,600,000
    unsigned* csr     = (unsigned*)(ws + 23232784);          //  6,000,000 (padded)
    int*      bsum    = (int*)(ws + 29232784);               //        392

    // 1) pack W into bf16 MFMA B-fragments + zero counts (fused, no memset)
    pack_w<<<(D_IN * D_OUT + 255) / 256, 256, 0, stream>>>(W, WpackS, counts);

    // 2) fused role-split GEMM (row-contiguous rotated staging) + edge
    gemm_hist_cv<<<FUSED_NB, 256, 0, stream>>>(
        x, (const bf16x8*)WpackS, support, erow, ecol, eval, counts, rcv);

    // 3) scan (2 launches: partial sums, then merged bsum-scan + emit)
    partial_k<<<SCAN_NB, 256, 0, stream>>>(counts, bsum);
    emit_k<<<SCAN_NB, 256, 0, stream>>>(counts, bsum, offsets);

    // 4) atomic-free predicated CSR fill, 2 L2-localized passes
    for (int p = 0; p < FILL_PASSES; ++p) {
        fill_k<<<FILL_NB, 256, 0, stream>>>(rcv, offsets, csr,
                                            p * PASS_NODES, (p + 1) * PASS_NODES);
    }

    // 5) aggregate + ReLU (no atomics, writes every output element)
    agg_k<<<(N_NODES + 15) / 16, 256, 0, stream>>>(offsets, counts, csr,
                                                   (const uint2*)support, out);
}

// Round 21
// 119.284 us; speedup vs baseline: 1.1370x; 1.0008x over previous
//
#include <hip/hip_runtime.h>
#include <hip/hip_bf16.h>

#define N_NODES 100000
#define N_EDGES 1200000
#define D_IN 256
#define D_OUT 64
#define N_TILES (N_NODES / 16)                     // 6250 row tiles of 16

#define NG 1280                                    // GEMM blocks = 5/CU x 256
#define FUSED_NB (NG * 2)                          // even: GEMM, odd: edge
#define EDGE4_NB ((N_EDGES / 4 + 255) / 256)       // 1172 (4 edges/thread)

#define FILL_PASSES 2
#define PASS_NODES (N_NODES / FILL_PASSES)         // 50000 (~3MB csr window, L2-resident)
#define FILL_NB ((N_EDGES / 4 + 255) / 256)        // 1172

#define SCAN_BLOCK 1024
#define SCAN_NB ((N_NODES + SCAN_BLOCK - 1) / SCAN_BLOCK) // 98

typedef __bf16 bf16_t;
typedef bf16_t bf16x8 __attribute__((ext_vector_type(8)));
typedef float f32x4 __attribute__((ext_vector_type(4)));

// pack (col, val) into 4B: col<<15 | round(val*32767). val in [0,1).
__device__ __forceinline__ unsigned pack_cv(int col, float val) {
    return ((unsigned)col << 15) | (unsigned)(val * 32767.f + 0.5f);
}

__device__ __forceinline__ bf16x8 cvt8(float4 lo, float4 hi) {
    bf16x8 a;
    a[0] = (bf16_t)lo.x; a[1] = (bf16_t)lo.y;
    a[2] = (bf16_t)lo.z; a[3] = (bf16_t)lo.w;
    a[4] = (bf16_t)hi.x; a[5] = (bf16_t)hi.y;
    a[6] = (bf16_t)hi.z; a[7] = (bf16_t)hi.w;
    return a;
}

// async global->LDS, 16B per lane, dest = wave-uniform base + lane*16
__device__ __forceinline__ void gld_lds16(const void* g, void* l) {
    __builtin_amdgcn_global_load_lds(
        (const __attribute__((address_space(1))) void*)g,
        (__attribute__((address_space(3))) void*)l, 16, 0, 0);
}

// ---------------------------------------------------------------------------
// Kernel 1: pack W[256][64] (fp32) into MFMA B-fragment order, bf16.
// Also zeros counts[] (grid-stride int4) -> drops the memset launch.
// ---------------------------------------------------------------------------
__global__ __launch_bounds__(256) void pack_w(const float* __restrict__ W,
                                              bf16_t* __restrict__ Wpack,
                                              int* __restrict__ counts) {
    int id = blockIdx.x * 256 + threadIdx.x;
    if (id < D_IN * D_OUT) {
        int i  = id & 7;
        int l  = (id >> 3) & 63;
        int n  = (id >> 9) & 3;
        int kk = id >> 11;
        int k = kk * 32 + (l >> 4) * 8 + i;
        int c = n * 16 + (l & 15);
        Wpack[id] = (bf16_t)W[k * D_OUT + c];
    }
    for (int i = id; i < N_NODES / 4; i += (D_IN * D_OUT / 256) * 256)
        ((int4*)counts)[i] = make_int4(0, 0, 0, 0);
}

// ---------------------------------------------------------------------------
// Stage one x tile (16 rows x 1KB) into LDS, one full row per instruction
// (64 lanes x 16B = 1KB contiguous global read). Rotation swizzle: slot s
// of row r holds chunk (s + r) & 63 (per-lane source, linear LDS dest).
// ---------------------------------------------------------------------------
__device__ __forceinline__ void stage_tile(const char* __restrict__ xtile,
                                           char* ldsbuf, int wave, int lane) {
#pragma unroll
    for (int i = 0; i < 4; ++i) {
        int r = wave + i * 4;
        const char* src = xtile + r * 1024 + (((lane + r) & 63) << 4);
        gld_lds16(src, ldsbuf + r * 1024);
    }
}

// Compute one tile from LDS (rotation-inverted reads), store its 16x16
// output sub-tile (cols wave*16..).
__device__ __forceinline__ void compute_store(const char* buf,
                                              const bf16x8* wf,
                                              int lane, int lrow, int g, int wave,
                                              bf16_t* __restrict__ support,
                                              int tile) {
    f32x4 acc = {0.f, 0.f, 0.f, 0.f};
    const char* rowp = buf + lrow * 1024;
#pragma unroll
    for (int kk = 0; kk < 8; ++kk) {
        int c = kk * 8 + g * 2;
        float4 lo = *(const float4*)(rowp + (((c     - lrow) & 63) << 4));
        float4 hi = *(const float4*)(rowp + (((c + 1 - lrow) & 63) << 4));
        acc = __builtin_amdgcn_mfma_f32_16x16x32_bf16(cvt8(lo, hi), wf[kk],
                                                      acc, 0, 0, 0);
    }
    bf16_t* __restrict__ sp = support + (size_t)tile * 16 * D_OUT
                            + wave * 16 + lrow;
#pragma unroll
    for (int q = 0; q < 4; ++q)
        sp[(g * 4 + q) * D_OUT] = (bf16_t)acc[q];
}

// ---------------------------------------------------------------------------
// Kernel 2 (fused, role-split): even blocks = GEMM (double-buffered
// global_load_lds pipeline, counted vmcnt); odd = edge chunk (hist atomics
// capturing pos, rcv pack).
// ---------------------------------------------------------------------------
__global__ __launch_bounds__(256, 5) void gemm_hist_cv(
        const float* __restrict__ x, const bf16x8* __restrict__ Wpack,
        bf16_t* __restrict__ support,
        const int* __restrict__ erow, const int* __restrict__ ecol,
        const float* __restrict__ eval,
        int* __restrict__ counts, unsigned* __restrict__ rcv) {
    __shared__ char xlds[2][16384];                // 32 KB double buffer
    int bid  = blockIdx.x;
    int role = bid & 1;
    int idx  = bid >> 1;
    if (role == 0) {
        // ---------------- GEMM role ----------------
        int lane = threadIdx.x & 63;
        int wave = threadIdx.x >> 6;
        int lrow = lane & 15;
        int g    = lane >> 4;

        // W fragments FIRST (oldest in VMEM FIFO; retired by first vmcnt(4))
        bf16x8 wf[8];
#pragma unroll
        for (int kk = 0; kk < 8; ++kk)
            wf[kk] = Wpack[(kk * 4 + wave) * 64 + lane];

        const char* xc = (const char*)x;
        int t = idx;                               // idx in [0, NG)
        stage_tile(xc + (size_t)t * 16384, xlds[0], wave, lane);

        int cur = 0;
#pragma unroll 1
        for (; t < N_TILES; t += NG) {
            int nxt = t + NG;
            if (nxt < N_TILES) {
                stage_tile(xc + (size_t)nxt * 16384, xlds[cur ^ 1], wave, lane);
                if (t == idx) {
                    asm volatile("s_waitcnt vmcnt(4)" ::: "memory");
                } else {
                    asm volatile("s_waitcnt vmcnt(8)" ::: "memory");
                }
            } else {
                asm volatile("s_waitcnt vmcnt(4)" ::: "memory");
            }
            __builtin_amdgcn_s_barrier();          // staged data visible
            __builtin_amdgcn_sched_barrier(0);     // pin ds_reads below
            compute_store(xlds[cur], wf, lane, lrow, g, wave, support, t);
            __builtin_amdgcn_s_barrier();          // all waves done reading
            __builtin_amdgcn_sched_barrier(0);     // pin next stage below
            cur ^= 1;
        }
    } else {
        // ---- edge role: histogram + pos capture + rcv pack ----
        if (idx >= EDGE4_NB) return;
        int e = (idx * 256 + threadIdx.x) * 4;
        if (e + 3 < N_EDGES) {
            int4   r4 = *(const int4*)(erow + e);
            int4   c4 = *(const int4*)(ecol + e);
            float4 v4 = *(const float4*)(eval + e);
            unsigned p0 = (unsigned)atomicAdd(&counts[r4.x], 1);
            unsigned p1 = (unsigned)atomicAdd(&counts[r4.y], 1);
            unsigned p2 = (unsigned)atomicAdd(&counts[r4.z], 1);
            unsigned p3 = (unsigned)atomicAdd(&counts[r4.w], 1);
            uint4 o1, o2;
            o1.x = pack_cv(c4.x, v4.x); o1.y = (unsigned)r4.x | (p0 << 17);
            o1.z = pack_cv(c4.y, v4.y); o1.w = (unsigned)r4.y | (p1 << 17);
            o2.x = pack_cv(c4.z, v4.z); o2.y = (unsigned)r4.z | (p2 << 17);
            o2.z = pack_cv(c4.w, v4.w); o2.w = (unsigned)r4.w | (p3 << 17);
            *(uint4*)(rcv + 2 * e)     = o1;
            *(uint4*)(rcv + 2 * e + 4) = o2;
        } else {
            for (int i = 0; i < 4; ++i) {
                if (e + i < N_EDGES) {
                    int rr = erow[e + i];
                    unsigned pp = (unsigned)atomicAdd(&counts[rr], 1);
                    rcv[2 * (e + i)]     = pack_cv(ecol[e + i], eval[e + i]);
                    rcv[2 * (e + i) + 1] = (unsigned)rr | (pp << 17);
                }
            }
        }
    }
}

// ---------------------------------------------------------------------------
// Kernel 3a: per-block partial sums of ceil4(counts) (quad-aligned segments).
// ---------------------------------------------------------------------------
__global__ __launch_bounds__(256) void partial_k(const int* __restrict__ counts,
                                                 int* __restrict__ bsum) {
    int b = blockIdx.x, t = threadIdx.x;
    int base = b * SCAN_BLOCK + t * 4;
    int s = 0;
    if (base + 3 < N_NODES) {
        int4 v = *(const int4*)(counts + base);
        s = ((v.x + 3) & ~3) + ((v.y + 3) & ~3) + ((v.z + 3) & ~3) + ((v.w + 3) & ~3);
    } else {
#pragma unroll
        for (int i = 0; i < 4; ++i)
            if (base + i < N_NODES) s += (counts[base + i] + 3) & ~3;
    }
#pragma unroll
    for (int off = 32; off > 0; off >>= 1) s += __shfl_down(s, off);
    __shared__ int sh[4];
    if ((t & 63) == 0) sh[t >> 6] = s;
    __syncthreads();
    if (t == 0) bsum[b] = sh[0] + sh[1] + sh[2] + sh[3];
}

// ---------------------------------------------------------------------------
// Kernel 3b: emit (merged with bsum scan): each block locally scans the 98
// block sums in LDS, then block-local scan of ceil4 degrees -> offsets.
// ---------------------------------------------------------------------------
__global__ __launch_bounds__(256) void emit_k(const int* __restrict__ counts,
                                              const int* __restrict__ bsum,
                                              int* __restrict__ offsets) {
    __shared__ int sb[128];
    __shared__ int sh[256];
    int b = blockIdx.x, t = threadIdx.x;
    if (t < 128) sb[t] = (t < SCAN_NB) ? bsum[t] : 0;
    __syncthreads();
    for (int off = 1; off < 128; off <<= 1) {
        int add = (t < 128 && t >= off) ? sb[t - off] : 0;
        __syncthreads();
        if (t < 128) sb[t] += add;
        __syncthreads();
    }
    int bpre = (b == 0) ? 0 : sb[b - 1];

    int base = b * SCAN_BLOCK + t * 4;
    int c0 = 0, c1 = 0, c2 = 0, c3 = 0;
    if (base + 3 < N_NODES) {
        int4 v = *(const int4*)(counts + base);
        c0 = (v.x + 3) & ~3; c1 = (v.y + 3) & ~3;
        c2 = (v.z + 3) & ~3; c3 = (v.w + 3) & ~3;
    } else {
        if (base + 0 < N_NODES) c0 = (counts[base + 0] + 3) & ~3;
        if (base + 1 < N_NODES) c1 = (counts[base + 1] + 3) & ~3;
        if (base + 2 < N_NODES) c2 = (counts[base + 2] + 3) & ~3;
        if (base + 3 < N_NODES) c3 = (counts[base + 3] + 3) & ~3;
    }
    int sum4 = c0 + c1 + c2 + c3;
    sh[t] = sum4;
    __syncthreads();
    for (int off = 1; off < 256; off <<= 1) {
        int add = (t >= off) ? sh[t - off] : 0;
        __syncthreads();
        sh[t] += add;
        __syncthreads();
    }
    int run = bpre + sh[t] - sum4;
    if (base + 0 < N_NODES) { offsets[base + 0] = run; run += c0; }
    if (base + 1 < N_NODES) { offsets[base + 1] = run; run += c1; }
    if (base + 2 < N_NODES) { offsets[base + 2] = run; run += c2; }
    if (base + 3 < N_NODES) { offsets[base + 3] = run; run += c3; }
}

// ---------------------------------------------------------------------------
// Kernel 4: atomic-free predicated CSR fill: dst = offsets[row] + pos.
// 2 passes, each confined to a ~3MB (L2-resident) csr window [lo, hi).
// ---------------------------------------------------------------------------
__global__ __launch_bounds__(256) void fill_k(const unsigned* __restrict__ rcv,
                                              const int* __restrict__ offsets,
                                              unsigned* __restrict__ csr,
                                              int lo, int hi) {
    int t = blockIdx.x * 256 + threadIdx.x;
    int e = t * 4;
    if (e + 3 < N_EDGES) {
        uint4 A = *(const uint4*)(rcv + 2 * e);
        uint4 B = *(const uint4*)(rcv + 2 * e + 4);
        int r0 = (int)(A.y & 0x1ffffu), p0 = (int)(A.y >> 17);
        int r1 = (int)(A.w & 0x1ffffu), p1 = (int)(A.w >> 17);
        int r2 = (int)(B.y & 0x1ffffu), p2 = (int)(B.y >> 17);
        int r3 = (int)(B.w & 0x1ffffu), p3 = (int)(B.w >> 17);
        int o0 = offsets[r0];
        int o1 = offsets[r1];
        int o2 = offsets[r2];
        int o3 = offsets[r3];
        if (r0 >= lo && r0 < hi) csr[o0 + p0] = A.x;
        if (r1 >= lo && r1 < hi) csr[o1 + p1] = A.z;
        if (r2 >= lo && r2 < hi) csr[o2 + p2] = B.x;
        if (r3 >= lo && r3 < hi) csr[o3 + p3] = B.z;
    } else {
        for (int i = 0; i < 4; ++i) {
            if (e + i < N_EDGES) {
                unsigned cw = rcv[2 * (e + i)];
                unsigned rw = rcv[2 * (e + i) + 1];
                int rr = (int)(rw & 0x1ffffu);
                int pp = (int)(rw >> 17);
                if (rr >= lo && rr < hi) csr[offsets[rr] + pp] = cw;
            }
        }
    }
}

// ---------------------------------------------------------------------------
// Kernel 5: aggregate + ReLU. 8 nodes/wave: 8 lanes x uint4 (16B = 8 bf16
// features) per node -> still 128B coalesced gather per edge, 8 independent
// node streams/wave (2x MLP vs 4-node). Macro params renamed (ew/qv) to
// avoid preprocessor collision with the .w member access.
// ---------------------------------------------------------------------------
__global__ __launch_bounds__(256) void agg_k(const int* __restrict__ offsets,
                                             const int* __restrict__ counts,
                                             const unsigned* __restrict__ csr,
                                             const uint4* __restrict__ sup16,
                                             float* __restrict__ out) {
    int wave = threadIdx.x >> 6;
    int lane = threadIdx.x & 63;
    int o8   = lane >> 3;
    int fl   = lane & 7;
    int node = blockIdx.x * 32 + wave * 8 + o8;
    if (node >= N_NODES) return;
    int s = offsets[node];
    int e = s + counts[node];
    const float inv = 1.f / 32767.f;
    float a0 = 0.f, a1 = 0.f, a2 = 0.f, a3 = 0.f;
    float a4 = 0.f, a5 = 0.f, a6 = 0.f, a7 = 0.f;
    int p = s;
#define ACC(ew, qv) { float vv = (float)((ew) & 0x7fffu) * inv;                 \
        unsigned qx = (qv).x, qy = (qv).y, qz = (qv).z, qw = (qv).w;            \
        a0 = fmaf(vv, __uint_as_float(qx << 16), a0);                           \
        a1 = fmaf(vv, __uint_as_float(qx & 0xffff0000u), a1);                   \
        a2 = fmaf(vv, __uint_as_float(qy << 16), a2);                           \
        a3 = fmaf(vv, __uint_as_float(qy & 0xffff0000u), a3);                   \
        a4 = fmaf(vv, __uint_as_float(qz << 16), a4);                           \
        a5 = fmaf(vv, __uint_as_float(qz & 0xffff0000u), a5);                   \
        a6 = fmaf(vv, __uint_as_float(qw << 16), a6);                           \
        a7 = fmaf(vv, __uint_as_float(qw & 0xffff0000u), a7); }
    for (; p + 8 <= e; p += 8) {
        uint4 A = *(const uint4*)(csr + p);
        uint4 B = *(const uint4*)(csr + p + 4);
        unsigned e0 = A.x, e1 = A.y, e2 = A.z, e3 = A.w;
        unsigned e4 = B.x, e5 = B.y, e6 = B.z, e7 = B.w;
        uint4 q0 = sup16[(size_t)(e0 >> 15) * 8 + fl];
        uint4 q1 = sup16[(size_t)(e1 >> 15) * 8 + fl];
        uint4 q2 = sup16[(size_t)(e2 >> 15) * 8 + fl];
        uint4 q3 = sup16[(size_t)(e3 >> 15) * 8 + fl];
        uint4 q4 = sup16[(size_t)(e4 >> 15) * 8 + fl];
        uint4 q5 = sup16[(size_t)(e5 >> 15) * 8 + fl];
        uint4 q6 = sup16[(size_t)(e6 >> 15) * 8 + fl];
        uint4 q7 = sup16[(size_t)(e7 >> 15) * 8 + fl];
        ACC(e0, q0) ACC(e1, q1) ACC(e2, q2) ACC(e3, q3)
        ACC(e4, q4) ACC(e5, q5) ACC(e6, q6) ACC(e7, q7)
    }
    if (p + 4 <= e) {
        uint4 A = *(const uint4*)(csr + p);
        unsigned e0 = A.x, e1 = A.y, e2 = A.z, e3 = A.w;
        uint4 q0 = sup16[(size_t)(e0 >> 15) * 8 + fl];
        uint4 q1 = sup16[(size_t)(e1 >> 15) * 8 + fl];
        uint4 q2 = sup16[(size_t)(e2 >> 15) * 8 + fl];
        uint4 q3 = sup16[(size_t)(e3 >> 15) * 8 + fl];
        ACC(e0, q0) ACC(e1, q1) ACC(e2, q2) ACC(e3, q3)
        p += 4;
    }
    for (; p < e; ++p) {
        unsigned ew = csr[p];
        uint4 qv = sup16[(size_t)(ew >> 15) * 8 + fl];
        ACC(ew, qv)
    }
#undef ACC
    float4 r1, r2;
    r1.x = fmaxf(a0, 0.f); r1.y = fmaxf(a1, 0.f);
    r1.z = fmaxf(a2, 0.f); r1.w = fmaxf(a3, 0.f);
    r2.x = fmaxf(a4, 0.f); r2.y = fmaxf(a5, 0.f);
    r2.z = fmaxf(a6, 0.f); r2.w = fmaxf(a7, 0.f);
    float* op = out + (size_t)node * D_OUT + fl * 8;
    *(float4*)op = r1;
    *(float4*)(op + 4) = r2;
}

extern "C" void kernel_launch(void* const* d_in, const int* in_sizes, int n_in,
                              void* d_out, int out_size, void* d_ws, size_t ws_size,
                              hipStream_t stream) {
    const float* x    = (const float*)d_in[0];
    const int*   erow = (const int*)d_in[1];
    const int*   ecol = (const int*)d_in[2];
    const float* eval = (const float*)d_in[3];
    const float* W    = (const float*)d_in[4];
    float* out = (float*)d_out;

    // ---- workspace layout (16B-aligned segments, ~29.3 MB) ----
    char* ws = (char*)d_ws;
    bf16_t*   support = (bf16_t*)ws;                         // 12,800,000
    bf16_t*   WpackS  = (bf16_t*)(ws + 12800000);            //     32,768
    int*      counts  = (int*)(ws + 12832768);               //    400,000
    int*      offsets = (int*)(ws + 13232768);               //    400,016
    unsigned* rcv     = (unsigned*)(ws + 13632784);          //  9,600,000
    unsigned* csr     = (unsigned*)(ws + 23232784);          //  6,000,000 (padded)
    int*      bsum    = (int*)(ws + 29232784);               //        392

    // 1) pack W into bf16 MFMA B-fragments + zero counts (fused, no memset)
    pack_w<<<(D_IN * D_OUT + 255) / 256, 256, 0, stream>>>(W, WpackS, counts);

    // 2) fused role-split GEMM (row-contiguous rotated staging) + edge
    gemm_hist_cv<<<FUSED_NB, 256, 0, stream>>>(
        x, (const bf16x8*)WpackS, support, erow, ecol, eval, counts, rcv);

    // 3) scan (2 launches: partial sums, then merged bsum-scan + emit)
    partial_k<<<SCAN_NB, 256, 0, stream>>>(counts, bsum);
    emit_k<<<SCAN_NB, 256, 0, stream>>>(counts, bsum, offsets);

    // 4) atomic-free predicated CSR fill, 2 L2-localized passes
    for (int p = 0; p < FILL_PASSES; ++p) {
        fill_k<<<FILL_NB, 256, 0, stream>>>(rcv, offsets, csr,
                                            p * PASS_NODES, (p + 1) * PASS_NODES);
    }

    // 5) aggregate + ReLU (no atomics, writes every output element)
    agg_k<<<(N_NODES + 31) / 32, 256, 0, stream>>>(offsets, counts, csr,
                                                   (const uint4*)support, out);
}

// Round 23
// 119.223 us; speedup vs baseline: 1.1375x; 1.0005x over previous
//
#include <hip/hip_runtime.h>
#include <hip/hip_bf16.h>

#define N_NODES 100000
#define N_EDGES 1200000
#define D_IN 256
#define D_OUT 64
#define N_TILES (N_NODES / 16)                     // 6250 row tiles of 16

#define NG 1280                                    // GEMM blocks = 5/CU x 256
#define FUSED_NB (NG * 2)                          // even: GEMM, odd: edge
#define EDGE4_NB ((N_EDGES / 4 + 255) / 256)       // 1172 (4 edges/thread)

#define FILL_PASSES 2
#define PASS_NODES (N_NODES / FILL_PASSES)         // 50000 (~3MB csr window, L2-resident)
#define FILL_NB ((N_EDGES / 4 + 255) / 256)        // 1172

#define SCAN_BLOCK 1024
#define SCAN_NB ((N_NODES + SCAN_BLOCK - 1) / SCAN_BLOCK) // 98

typedef __bf16 bf16_t;
typedef bf16_t bf16x8 __attribute__((ext_vector_type(8)));
typedef float f32x4 __attribute__((ext_vector_type(4)));

// pack (col, val) into 4B: col<<15 | round(val*32767). val in [0,1).
__device__ __forceinline__ unsigned pack_cv(int col, float val) {
    return ((unsigned)col << 15) | (unsigned)(val * 32767.f + 0.5f);
}

__device__ __forceinline__ bf16x8 cvt8(float4 lo, float4 hi) {
    bf16x8 a;
    a[0] = (bf16_t)lo.x; a[1] = (bf16_t)lo.y;
    a[2] = (bf16_t)lo.z; a[3] = (bf16_t)lo.w;
    a[4] = (bf16_t)hi.x; a[5] = (bf16_t)hi.y;
    a[6] = (bf16_t)hi.z; a[7] = (bf16_t)hi.w;
    return a;
}

// async global->LDS, 16B per lane, dest = wave-uniform base + lane*16
__device__ __forceinline__ void gld_lds16(const void* g, void* l) {
    __builtin_amdgcn_global_load_lds(
        (const __attribute__((address_space(1))) void*)g,
        (__attribute__((address_space(3))) void*)l, 16, 0, 0);
}

// ---------------------------------------------------------------------------
// Kernel 1: pack W[256][64] (fp32) into MFMA B-fragment order, bf16.
// Also zeros counts[] (grid-stride int4) -> drops the memset launch.
// ---------------------------------------------------------------------------
__global__ __launch_bounds__(256) void pack_w(const float* __restrict__ W,
                                              bf16_t* __restrict__ Wpack,
                                              int* __restrict__ counts) {
    int id = blockIdx.x * 256 + threadIdx.x;
    if (id < D_IN * D_OUT) {
        int i  = id & 7;
        int l  = (id >> 3) & 63;
        int n  = (id >> 9) & 3;
        int kk = id >> 11;
        int k = kk * 32 + (l >> 4) * 8 + i;
        int c = n * 16 + (l & 15);
        Wpack[id] = (bf16_t)W[k * D_OUT + c];
    }
    for (int i = id; i < N_NODES / 4; i += (D_IN * D_OUT / 256) * 256)
        ((int4*)counts)[i] = make_int4(0, 0, 0, 0);
}

// ---------------------------------------------------------------------------
// Stage one x tile (16 rows x 1KB) into LDS, one full row per instruction
// (64 lanes x 16B = 1KB contiguous global read). Rotation swizzle: slot s
// of row r holds chunk (s + r) & 63 (per-lane source, linear LDS dest).
// ---------------------------------------------------------------------------
__device__ __forceinline__ void stage_tile(const char* __restrict__ xtile,
                                           char* ldsbuf, int wave, int lane) {
#pragma unroll
    for (int i = 0; i < 4; ++i) {
        int r = wave + i * 4;
        const char* src = xtile + r * 1024 + (((lane + r) & 63) << 4);
        gld_lds16(src, ldsbuf + r * 1024);
    }
}

// Compute one tile from LDS (rotation-inverted reads), store its 16x16
// output sub-tile (cols wave*16..).
__device__ __forceinline__ void compute_store(const char* buf,
                                              const bf16x8* wf,
                                              int lane, int lrow, int g, int wave,
                                              bf16_t* __restrict__ support,
                                              int tile) {
    f32x4 acc = {0.f, 0.f, 0.f, 0.f};
    const char* rowp = buf + lrow * 1024;
#pragma unroll
    for (int kk = 0; kk < 8; ++kk) {
        int c = kk * 8 + g * 2;
        float4 lo = *(const float4*)(rowp + (((c     - lrow) & 63) << 4));
        float4 hi = *(const float4*)(rowp + (((c + 1 - lrow) & 63) << 4));
        acc = __builtin_amdgcn_mfma_f32_16x16x32_bf16(cvt8(lo, hi), wf[kk],
                                                      acc, 0, 0, 0);
    }
    bf16_t* __restrict__ sp = support + (size_t)tile * 16 * D_OUT
                            + wave * 16 + lrow;
#pragma unroll
    for (int q = 0; q < 4; ++q)
        sp[(g * 4 + q) * D_OUT] = (bf16_t)acc[q];
}

// ---------------------------------------------------------------------------
// Kernel 2 (fused, role-split): even blocks = GEMM (double-buffered
// global_load_lds pipeline, counted vmcnt); odd = edge chunk (hist atomics
// capturing pos, rcv pack).
// ---------------------------------------------------------------------------
__global__ __launch_bounds__(256, 5) void gemm_hist_cv(
        const float* __restrict__ x, const bf16x8* __restrict__ Wpack,
        bf16_t* __restrict__ support,
        const int* __restrict__ erow, const int* __restrict__ ecol,
        const float* __restrict__ eval,
        int* __restrict__ counts, unsigned* __restrict__ rcv) {
    __shared__ char xlds[2][16384];                // 32 KB double buffer
    int bid  = blockIdx.x;
    int role = bid & 1;
    int idx  = bid >> 1;
    if (role == 0) {
        // ---------------- GEMM role ----------------
        int lane = threadIdx.x & 63;
        int wave = threadIdx.x >> 6;
        int lrow = lane & 15;
        int g    = lane >> 4;

        // W fragments FIRST (oldest in VMEM FIFO; retired by first vmcnt(4))
        bf16x8 wf[8];
#pragma unroll
        for (int kk = 0; kk < 8; ++kk)
            wf[kk] = Wpack[(kk * 4 + wave) * 64 + lane];

        const char* xc = (const char*)x;
        int t = idx;                               // idx in [0, NG)
        stage_tile(xc + (size_t)t * 16384, xlds[0], wave, lane);

        int cur = 0;
#pragma unroll 1
        for (; t < N_TILES; t += NG) {
            int nxt = t + NG;
            if (nxt < N_TILES) {
                stage_tile(xc + (size_t)nxt * 16384, xlds[cur ^ 1], wave, lane);
                if (t == idx) {
                    asm volatile("s_waitcnt vmcnt(4)" ::: "memory");
                } else {
                    asm volatile("s_waitcnt vmcnt(8)" ::: "memory");
                }
            } else {
                asm volatile("s_waitcnt vmcnt(4)" ::: "memory");
            }
            __builtin_amdgcn_s_barrier();          // staged data visible
            __builtin_amdgcn_sched_barrier(0);     // pin ds_reads below
            compute_store(xlds[cur], wf, lane, lrow, g, wave, support, t);
            __builtin_amdgcn_s_barrier();          // all waves done reading
            __builtin_amdgcn_sched_barrier(0);     // pin next stage below
            cur ^= 1;
        }
    } else {
        // ---- edge role: histogram + pos capture + rcv pack ----
        if (idx >= EDGE4_NB) return;
        int e = (idx * 256 + threadIdx.x) * 4;
        if (e + 3 < N_EDGES) {
            int4   r4 = *(const int4*)(erow + e);
            int4   c4 = *(const int4*)(ecol + e);
            float4 v4 = *(const float4*)(eval + e);
            unsigned p0 = (unsigned)atomicAdd(&counts[r4.x], 1);
            unsigned p1 = (unsigned)atomicAdd(&counts[r4.y], 1);
            unsigned p2 = (unsigned)atomicAdd(&counts[r4.z], 1);
            unsigned p3 = (unsigned)atomicAdd(&counts[r4.w], 1);
            uint4 o1, o2;
            o1.x = pack_cv(c4.x, v4.x); o1.y = (unsigned)r4.x | (p0 << 17);
            o1.z = pack_cv(c4.y, v4.y); o1.w = (unsigned)r4.y | (p1 << 17);
            o2.x = pack_cv(c4.z, v4.z); o2.y = (unsigned)r4.z | (p2 << 17);
            o2.z = pack_cv(c4.w, v4.w); o2.w = (unsigned)r4.w | (p3 << 17);
            *(uint4*)(rcv + 2 * e)     = o1;
            *(uint4*)(rcv + 2 * e + 4) = o2;
        } else {
            for (int i = 0; i < 4; ++i) {
                if (e + i < N_EDGES) {
                    int rr = erow[e + i];
                    unsigned pp = (unsigned)atomicAdd(&counts[rr], 1);
                    rcv[2 * (e + i)]     = pack_cv(ecol[e + i], eval[e + i]);
                    rcv[2 * (e + i) + 1] = (unsigned)rr | (pp << 17);
                }
            }
        }
    }
}

// ---------------------------------------------------------------------------
// Kernel 3a: per-block partial sums of ceil4(counts) (quad-aligned segments).
// ---------------------------------------------------------------------------
__global__ __launch_bounds__(256) void partial_k(const int* __restrict__ counts,
                                                 int* __restrict__ bsum) {
    int b = blockIdx.x, t = threadIdx.x;
    int base = b * SCAN_BLOCK + t * 4;
    int s = 0;
    if (base + 3 < N_NODES) {
        int4 v = *(const int4*)(counts + base);
        s = ((v.x + 3) & ~3) + ((v.y + 3) & ~3) + ((v.z + 3) & ~3) + ((v.w + 3) & ~3);
    } else {
#pragma unroll
        for (int i = 0; i < 4; ++i)
            if (base + i < N_NODES) s += (counts[base + i] + 3) & ~3;
    }
#pragma unroll
    for (int off = 32; off > 0; off >>= 1) s += __shfl_down(s, off);
    __shared__ int sh[4];
    if ((t & 63) == 0) sh[t >> 6] = s;
    __syncthreads();
    if (t == 0) bsum[b] = sh[0] + sh[1] + sh[2] + sh[3];
}

// ---------------------------------------------------------------------------
// Kernel 3b: emit (merged with bsum scan): each block locally scans the 98
// block sums in LDS, then block-local scan of ceil4 degrees -> offsets.
// ---------------------------------------------------------------------------
__global__ __launch_bounds__(256) void emit_k(const int* __restrict__ counts,
                                              const int* __restrict__ bsum,
                                              int* __restrict__ offsets) {
    __shared__ int sb[128];
    __shared__ int sh[256];
    int b = blockIdx.x, t = threadIdx.x;
    if (t < 128) sb[t] = (t < SCAN_NB) ? bsum[t] : 0;
    __syncthreads();
    for (int off = 1; off < 128; off <<= 1) {
        int add = (t < 128 && t >= off) ? sb[t - off] : 0;
        __syncthreads();
        if (t < 128) sb[t] += add;
        __syncthreads();
    }
    int bpre = (b == 0) ? 0 : sb[b - 1];

    int base = b * SCAN_BLOCK + t * 4;
    int c0 = 0, c1 = 0, c2 = 0, c3 = 0;
    if (base + 3 < N_NODES) {
        int4 v = *(const int4*)(counts + base);
        c0 = (v.x + 3) & ~3; c1 = (v.y + 3) & ~3;
        c2 = (v.z + 3) & ~3; c3 = (v.w + 3) & ~3;
    } else {
        if (base + 0 < N_NODES) c0 = (counts[base + 0] + 3) & ~3;
        if (base + 1 < N_NODES) c1 = (counts[base + 1] + 3) & ~3;
        if (base + 2 < N_NODES) c2 = (counts[base + 2] + 3) & ~3;
        if (base + 3 < N_NODES) c3 = (counts[base + 3] + 3) & ~3;
    }
    int sum4 = c0 + c1 + c2 + c3;
    sh[t] = sum4;
    __syncthreads();
    for (int off = 1; off < 256; off <<= 1) {
        int add = (t >= off) ? sh[t - off] : 0;
        __syncthreads();
        sh[t] += add;
        __syncthreads();
    }
    int run = bpre + sh[t] - sum4;
    if (base + 0 < N_NODES) { offsets[base + 0] = run; run += c0; }
    if (base + 1 < N_NODES) { offsets[base + 1] = run; run += c1; }
    if (base + 2 < N_NODES) { offsets[base + 2] = run; run += c2; }
    if (base + 3 < N_NODES) { offsets[base + 3] = run; run += c3; }
}

// ---------------------------------------------------------------------------
// Kernel 4: atomic-free predicated CSR fill: dst = offsets[row] + pos.
// 2 passes, each confined to a ~3MB (L2-resident) csr window [lo, hi).
// ---------------------------------------------------------------------------
__global__ __launch_bounds__(256) void fill_k(const unsigned* __restrict__ rcv,
                                              const int* __restrict__ offsets,
                                              unsigned* __restrict__ csr,
                                              int lo, int hi) {
    int t = blockIdx.x * 256 + threadIdx.x;
    int e = t * 4;
    if (e + 3 < N_EDGES) {
        uint4 A = *(const uint4*)(rcv + 2 * e);
        uint4 B = *(const uint4*)(rcv + 2 * e + 4);
        int r0 = (int)(A.y & 0x1ffffu), p0 = (int)(A.y >> 17);
        int r1 = (int)(A.w & 0x1ffffu), p1 = (int)(A.w >> 17);
        int r2 = (int)(B.y & 0x1ffffu), p2 = (int)(B.y >> 17);
        int r3 = (int)(B.w & 0x1ffffu), p3 = (int)(B.w >> 17);
        int o0 = offsets[r0];
        int o1 = offsets[r1];
        int o2 = offsets[r2];
        int o3 = offsets[r3];
        if (r0 >= lo && r0 < hi) csr[o0 + p0] = A.x;
        if (r1 >= lo && r1 < hi) csr[o1 + p1] = A.z;
        if (r2 >= lo && r2 < hi) csr[o2 + p2] = B.x;
        if (r3 >= lo && r3 < hi) csr[o3 + p3] = B.z;
    } else {
        for (int i = 0; i < 4; ++i) {
            if (e + i < N_EDGES) {
                unsigned cw = rcv[2 * (e + i)];
                unsigned rw = rcv[2 * (e + i) + 1];
                int rr = (int)(rw & 0x1ffffu);
                int pp = (int)(rw >> 17);
                if (rr >= lo && rr < hi) csr[offsets[rr] + pp] = cw;
            }
        }
    }
}

// ---------------------------------------------------------------------------
// Kernel 5: aggregate + ReLU. 8 nodes/wave: 8 lanes x uint4 (16B = 8 bf16
// features) per node -> 128B coalesced gather per edge, 8 independent node
// streams/wave.
// ---------------------------------------------------------------------------
__global__ __launch_bounds__(256) void agg_k(const int* __restrict__ offsets,
                                             const int* __restrict__ counts,
                                             const unsigned* __restrict__ csr,
                                             const uint4* __restrict__ sup16,
                                             float* __restrict__ out) {
    int wave = threadIdx.x >> 6;
    int lane = threadIdx.x & 63;
    int o8   = lane >> 3;
    int fl   = lane & 7;
    int node = blockIdx.x * 32 + wave * 8 + o8;
    if (node >= N_NODES) return;
    int s = offsets[node];
    int e = s + counts[node];
    const float inv = 1.f / 32767.f;
    float a0 = 0.f, a1 = 0.f, a2 = 0.f, a3 = 0.f;
    float a4 = 0.f, a5 = 0.f, a6 = 0.f, a7 = 0.f;
    int p = s;
#define ACC(ew, qv) { float vv = (float)((ew) & 0x7fffu) * inv;                 \
        unsigned qx = (qv).x, qy = (qv).y, qz = (qv).z, qw = (qv).w;            \
        a0 = fmaf(vv, __uint_as_float(qx << 16), a0);                           \
        a1 = fmaf(vv, __uint_as_float(qx & 0xffff0000u), a1);                   \
        a2 = fmaf(vv, __uint_as_float(qy << 16), a2);                           \
        a3 = fmaf(vv, __uint_as_float(qy & 0xffff0000u), a3);                   \
        a4 = fmaf(vv, __uint_as_float(qz << 16), a4);                           \
        a5 = fmaf(vv, __uint_as_float(qz & 0xffff0000u), a5);                   \
        a6 = fmaf(vv, __uint_as_float(qw << 16), a6);                           \
        a7 = fmaf(vv, __uint_as_float(qw & 0xffff0000u), a7); }
    for (; p + 8 <= e; p += 8) {
        uint4 A = *(const uint4*)(csr + p);
        uint4 B = *(const uint4*)(csr + p + 4);
        unsigned e0 = A.x, e1 = A.y, e2 = A.z, e3 = A.w;
        unsigned e4 = B.x, e5 = B.y, e6 = B.z, e7 = B.w;
        uint4 q0 = sup16[(size_t)(e0 >> 15) * 8 + fl];
        uint4 q1 = sup16[(size_t)(e1 >> 15) * 8 + fl];
        uint4 q2 = sup16[(size_t)(e2 >> 15) * 8 + fl];
        uint4 q3 = sup16[(size_t)(e3 >> 15) * 8 + fl];
        uint4 q4 = sup16[(size_t)(e4 >> 15) * 8 + fl];
        uint4 q5 = sup16[(size_t)(e5 >> 15) * 8 + fl];
        uint4 q6 = sup16[(size_t)(e6 >> 15) * 8 + fl];
        uint4 q7 = sup16[(size_t)(e7 >> 15) * 8 + fl];
        ACC(e0, q0) ACC(e1, q1) ACC(e2, q2) ACC(e3, q3)
        ACC(e4, q4) ACC(e5, q5) ACC(e6, q6) ACC(e7, q7)
    }
    if (p + 4 <= e) {
        uint4 A = *(const uint4*)(csr + p);
        unsigned e0 = A.x, e1 = A.y, e2 = A.z, e3 = A.w;
        uint4 q0 = sup16[(size_t)(e0 >> 15) * 8 + fl];
        uint4 q1 = sup16[(size_t)(e1 >> 15) * 8 + fl];
        uint4 q2 = sup16[(size_t)(e2 >> 15) * 8 + fl];
        uint4 q3 = sup16[(size_t)(e3 >> 15) * 8 + fl];
        ACC(e0, q0) ACC(e1, q1) ACC(e2, q2) ACC(e3, q3)
        p += 4;
    }
    for (; p < e; ++p) {
        unsigned ew = csr[p];
        uint4 qv = sup16[(size_t)(ew >> 15) * 8 + fl];
        ACC(ew, qv)
    }
#undef ACC
    float4 r1, r2;
    r1.x = fmaxf(a0, 0.f); r1.y = fmaxf(a1, 0.f);
    r1.z = fmaxf(a2, 0.f); r1.w = fmaxf(a3, 0.f);
    r2.x = fmaxf(a4, 0.f); r2.y = fmaxf(a5, 0.f);
    r2.z = fmaxf(a6, 0.f); r2.w = fmaxf(a7, 0.f);
    float* op = out + (size_t)node * D_OUT + fl * 8;
    *(float4*)op = r1;
    *(float4*)(op + 4) = r2;
}

extern "C" void kernel_launch(void* const* d_in, const int* in_sizes, int n_in,
                              void* d_out, int out_size, void* d_ws, size_t ws_size,
                              hipStream_t stream) {
    const float* x    = (const float*)d_in[0];
    const int*   erow = (const int*)d_in[1];
    const int*   ecol = (const int*)d_in[2];
    const float* eval = (const float*)d_in[3];
    const float* W    = (const float*)d_in[4];
    float* out = (float*)d_out;

    // ---- workspace layout (16B-aligned segments, ~29.3 MB) ----
    char* ws = (char*)d_ws;
    bf16_t*   support = (bf16_t*)ws;                         // 12,800,000
    bf16_t*   WpackS  = (bf16_t*)(ws + 12800000);            //     32,768
    int*      counts  = (int*)(ws + 12832768);               //    400,000
    int*      offsets = (int*)(ws + 13232768);               //    400,016
    unsigned* rcv     = (unsigned*)(ws + 13632784);          //  9,600,000
    unsigned* csr     = (unsigned*)(ws + 23232784);          //  6,000,000 (padded)
    int*      bsum    = (int*)(ws + 29232784);               //        392

    // 1) pack W into bf16 MFMA B-fragments + zero counts (fused, no memset)
    pack_w<<<(D_IN * D_OUT + 255) / 256, 256, 0, stream>>>(W, WpackS, counts);

    // 2) fused role-split GEMM (row-contiguous rotated staging) + edge
    gemm_hist_cv<<<FUSED_NB, 256, 0, stream>>>(
        x, (const bf16x8*)WpackS, support, erow, ecol, eval, counts, rcv);

    // 3) scan (2 launches: partial sums, then merged bsum-scan + emit)
    partial_k<<<SCAN_NB, 256, 0, stream>>>(counts, bsum);
    emit_k<<<SCAN_NB, 256, 0, stream>>>(counts, bsum, offsets);

    // 4) atomic-free predicated CSR fill, 2 L2-localized passes
    for (int p = 0; p < FILL_PASSES; ++p) {
        fill_k<<<FILL_NB, 256, 0, stream>>>(rcv, offsets, csr,
                                            p * PASS_NODES, (p + 1) * PASS_NODES);
    }

    // 5) aggregate + ReLU (no atomics, writes every output element)
    agg_k<<<(N_NODES + 31) / 32, 256, 0, stream>>>(offsets, counts, csr,
                                                   (const uint4*)support, out);
}